// Round 22
// baseline (911.390 us; speedup 1.0000x reference)
//
#include <hip/hip_runtime.h>
#include <hip/hip_bf16.h>
#include <stdint.h>

#define IN_F 2048
#define OUT_F 128
#define KD 32
#define NR 256
#define OC 2176          // IN_F + OUT_F
#define OD 4096          // OUT_F * KD (T row stride)
#define THRESH 32.0f
#define KSN 16           // k-slices of 128
#define OPN (512 * 256)  // elems per Pp partial (4 projections per f)

typedef __bf16 bf16x8 __attribute__((ext_vector_type(8)));
typedef __bf16 bf16x4 __attribute__((ext_vector_type(4)));
typedef float  f32x4  __attribute__((ext_vector_type(4)));
typedef uint16_t u16x4 __attribute__((ext_vector_type(4)));

// ---------------------------------------------------------------------------
// K1: fused tproj + sgemm + x-copy (R17 structure, 4 projections).
// Block = (ks in [0,16), fo in [0,32)). T slab read once -> butterfly
// (masks 1,2,4,8) -> Bs[16 o'][136]; x staged inline as MFMA A-frags
// (dbuf); 16 MFMA/block; epilogue bf16 Pp[ks][o'=f*4+p][n].
// ---------------------------------------------------------------------------
__global__ __launch_bounds__(256, 2) void fused_kernel(const float* __restrict__ x,
                                                       const float* __restrict__ Tm,
                                                       float* __restrict__ out,
                                                       __bf16* __restrict__ Pp) {
    __shared__ __bf16 Bs[16][136];       // Tproj slab [o'_local][k_local], pad 8
    __shared__ __bf16 As[2][4][256][8];  // x A-frag dbuf (32 KB)

    const int tid  = threadIdx.x;
    const int lane = tid & 63;
    const int wid  = tid >> 6;
    const int fr   = lane & 15, fg = lane >> 4;
    const int bid  = blockIdx.x;
    const int ks   = bid & 15;
    const int fo   = bid >> 4;           // f-group of 4
    const int k0   = ks * 128;

    // ---- x -> out copy (block covers 4 KB: row bid>>1, half bid&1)
    {
        const int row = bid >> 1;
        const int off = (bid & 1) * 1024 + tid * 4;
        float4 v = *reinterpret_cast<const float4*>(&x[row * IN_F + off]);
        *reinterpret_cast<float4*>(&out[row * OC + off]) = v;
    }

    // ---- issue x chunk-0 loads early (latency hides under butterflies)
    float4 xs[8];
    const int kslot = tid & 7;
    const int nrow8 = tid >> 3;          // n = p*32 + nrow8
    #pragma unroll
    for (int p = 0; p < 8; ++p)
        xs[p] = *reinterpret_cast<const float4*>(&x[(p * 32 + nrow8) * IN_F + k0 + kslot * 4]);

    // ---- tproj: 2 (k,f) pairs per thread; masks {1,2,4,8} via butterfly
    #pragma unroll 1
    for (int r = 0; r < 2; ++r) {
        const int idx = r * 256 + tid;
        const int fl  = idx & 3;
        const int kl  = idx >> 2;        // 0..127
        const float* src = Tm + (size_t)(k0 + kl) * OD + (fo * 4 + fl) * KD;

        float v[32];
        #pragma unroll
        for (int q = 0; q < 8; ++q) {
            f32x4 w = *reinterpret_cast<const f32x4*>(src + q * 4);
            v[q * 4]     = w[0];
            v[q * 4 + 1] = w[1];
            v[q * 4 + 2] = w[2];
            v[q * 4 + 3] = w[3];
        }

        float s1[16], d1[16];
        #pragma unroll
        for (int e = 0; e < 16; ++e) { s1[e] = v[2*e] + v[2*e+1]; d1[e] = v[2*e] - v[2*e+1]; }
        float s2[8], d2[8];
        #pragma unroll
        for (int e = 0; e < 8; ++e)  { s2[e] = s1[2*e] + s1[2*e+1]; d2[e] = s1[2*e] - s1[2*e+1]; }
        float s3[4], d3[4];
        #pragma unroll
        for (int e = 0; e < 4; ++e)  { s3[e] = s2[2*e] + s2[2*e+1]; d3[e] = s2[2*e] - s2[2*e+1]; }

        float pr[4];
        { float s = 0.f;                                   // mask 1 (bit0)
          #pragma unroll
          for (int e = 0; e < 16; ++e) s += d1[e];
          pr[0] = s; }
        { float s = 0.f;                                   // mask 2 (bit1)
          #pragma unroll
          for (int e = 0; e < 8; ++e) s += d2[e];
          pr[1] = s; }
        pr[2] = (d3[0] + d3[1]) + (d3[2] + d3[3]);         // mask 4 (bit2)
        pr[3] = (s3[0] - s3[1]) + (s3[2] - s3[3]);         // mask 8 (bit3)

        #pragma unroll
        for (int pp = 0; pp < 4; ++pp) {
            const int p = (pp + fl) & 3;                   // rotated write order
            Bs[fl * 4 + p][kl] = (__bf16)pr[p];
        }
    }

    // ---- write x chunk 0 into As[0]
    #pragma unroll
    for (int p = 0; p < 8; ++p) {
        bf16x4 b = { (__bf16)xs[p].x, (__bf16)xs[p].y, (__bf16)xs[p].z, (__bf16)xs[p].w };
        *reinterpret_cast<bf16x4*>(&As[0][kslot >> 1][p * 32 + nrow8][(kslot & 1) * 4]) = b;
    }
    __syncthreads();

    // ---- MFMA loop: 4 chunks of 32 k; wave owns 64 n x 16 o'
    f32x4 acc[4] = {};

    #pragma unroll 1
    for (int c = 0; c < 4; ++c) {
        const int buf = c & 1;
        if (c < 3) {
            #pragma unroll
            for (int p = 0; p < 8; ++p)
                xs[p] = *reinterpret_cast<const float4*>(
                    &x[(p * 32 + nrow8) * IN_F + k0 + (c + 1) * 32 + kslot * 4]);
        }

        const bf16x8 bfrag = *reinterpret_cast<const bf16x8*>(&Bs[fr][c * 32 + fg * 8]);
        #pragma unroll
        for (int mi = 0; mi < 4; ++mi) {
            bf16x8 af = *reinterpret_cast<const bf16x8*>(&As[buf][fg][wid * 64 + mi * 16 + fr][0]);
            acc[mi] = __builtin_amdgcn_mfma_f32_16x16x32_bf16(af, bfrag, acc[mi], 0, 0, 0);
        }

        if (c < 3) {
            __syncthreads();             // all waves done with As[buf^1] readers
            #pragma unroll
            for (int p = 0; p < 8; ++p) {
                bf16x4 b = { (__bf16)xs[p].x, (__bf16)xs[p].y, (__bf16)xs[p].z, (__bf16)xs[p].w };
                *reinterpret_cast<bf16x4*>(&As[buf ^ 1][kslot >> 1][p * 32 + nrow8][(kslot & 1) * 4]) = b;
            }
            __syncthreads();
        }
    }

    // ---- epilogue: Pp[ks][o' = fo*16 + fr][n = wid*64+mi*16+fg*4+r] bf16
    __bf16* dst = Pp + (size_t)ks * OPN;
    const int op = fo * 16 + fr;
    #pragma unroll
    for (int mi = 0; mi < 4; ++mi) {
        const int nb = wid * 64 + mi * 16 + fg * 4;
        bf16x4 v = { (__bf16)acc[mi][0], (__bf16)acc[mi][1],
                     (__bf16)acc[mi][2], (__bf16)acc[mi][3] };
        *reinterpret_cast<bf16x4*>(&dst[(size_t)op * NR + nb]) = v;
    }
}

// ---------------------------------------------------------------------------
// K2: screen (R17 broadcast hot loop, 4 projections). Staged merged
// projections (16 bf16 partials, u16x4); hot loop = ONE broadcast
// ds_read_b128 + 4 |d| + max tree. Drop pair when max_p |dproj| > 32
// (sound: L1 >= |dproj|; margins leave dropped terms <= 256*e^-17 ~ 1e-5
// << 0.099). Survivor (~2.5e-5/pair) -> exact norm on the fly from x,T.
// ---------------------------------------------------------------------------
__global__ __launch_bounds__(256, 2) void screen_kernel(const __bf16* __restrict__ Pp,
                                                        const float* __restrict__ x,
                                                        const float* __restrict__ Tm,
                                                        float* __restrict__ out) {
    __shared__ float P4s[256][4];
    __shared__ float part[4][64];

    const int f    = blockIdx.x;
    const int jq   = blockIdx.y;
    const int tid  = threadIdx.x;
    const int lane = tid & 63;
    const int wid  = tid >> 6;
    const int j    = jq * 64 + lane;

    // stage: thread t sums (p = t>>6, n = (t&63)*4 .. +4) over 16 partials
    {
        const int p  = tid >> 6;
        const int n0 = (tid & 63) * 4;
        const uint16_t* base = reinterpret_cast<const uint16_t*>(Pp)
                             + (size_t)(f * 4 + p) * NR + n0;
        float a[4] = {};
        #pragma unroll
        for (int ks = 0; ks < KSN; ++ks) {
            u16x4 v = *reinterpret_cast<const u16x4*>(base + (size_t)ks * OPN);
            #pragma unroll
            for (int e = 0; e < 4; ++e)
                a[e] += __builtin_bit_cast(float, (uint32_t)v[e] << 16);
        }
        #pragma unroll
        for (int e = 0; e < 4; ++e)
            P4s[n0 + e][p] = a[e];
    }
    __syncthreads();

    const f32x4 qj = *reinterpret_cast<const f32x4*>(&P4s[j][0]);

    float acc = 0.f;
    const int i0 = wid * 64;
    #pragma unroll 4
    for (int ii = 0; ii < 64; ++ii) {
        const int i = i0 + ii;
        f32x4 r = *reinterpret_cast<const f32x4*>(&P4s[i][0]);    // broadcast
        f32x4 d = r - qj;
        const float mx = fmaxf(fmaxf(fabsf(d[0]), fabsf(d[1])),
                               fmaxf(fabsf(d[2]), fabsf(d[3])));

        const bool ok = (mx < THRESH) && (i != j);
        if (__builtin_expect(__any(ok), 0)) {
            if (ok) {
                f32x4 ad[8] = {};
                const float* xi = x + (size_t)i * IN_F;
                const float* xj = x + (size_t)j * IN_F;
                for (int k = 0; k < IN_F; ++k) {
                    const float dk = xi[k] - xj[k];
                    const float* tr = Tm + (size_t)k * OD + f * KD;
                    #pragma unroll
                    for (int q = 0; q < 8; ++q) {
                        f32x4 tv = *reinterpret_cast<const f32x4*>(tr + q * 4);
                        ad[q] += dk * tv;
                    }
                }
                float norm = 0.f;
                #pragma unroll
                for (int q = 0; q < 8; ++q)
                    norm += fabsf(ad[q][0]) + fabsf(ad[q][1])
                          + fabsf(ad[q][2]) + fabsf(ad[q][3]);
                acc += __expf(-norm);
            }
        }
    }

    if (wid == jq) acc += 1.0f;          // diagonal exp(0)=1, exact

    part[wid][lane] = acc;
    __syncthreads();
    if (tid < 64) {
        float s = part[0][tid] + part[1][tid] + part[2][tid] + part[3][tid];
        out[(jq * 64 + tid) * OC + IN_F + f] = s;
    }
}

extern "C" void kernel_launch(void* const* d_in, const int* in_sizes, int n_in,
                              void* d_out, int out_size, void* d_ws, size_t ws_size,
                              hipStream_t stream) {
    const float* x  = (const float*)d_in[0];   // [256, 2048] f32
    const float* Tm = (const float*)d_in[1];   // [2048, 4096] f32
    float* out = (float*)d_out;                // [256, 2176] f32

    __bf16* Pp = (__bf16*)d_ws;                // 4 MB: 16 bf16 o'-major partials

    fused_kernel<<<dim3(512), 256, 0, stream>>>(x, Tm, out, Pp);
    screen_kernel<<<dim3(128, 4), 256, 0, stream>>>(Pp, x, Tm, out);
}

// Round 23
// 27.508 us; speedup vs baseline: 33.1322x; 33.1322x over previous
//
#include <hip/hip_runtime.h>
#include <hip/hip_bf16.h>
#include <stdint.h>

#define IN_F 2048
#define OUT_F 128
#define KD 32
#define NR 256
#define OC 2176          // IN_F + OUT_F
#define OD 4096          // OUT_F * KD (T row stride)
#define THRESH 32.0f
#define KSN 16           // k-slices of 128
#define OPN (1024 * 256) // elems per Pp partial (8 projections per f)

typedef __bf16 bf16x8 __attribute__((ext_vector_type(8)));
typedef __bf16 bf16x4 __attribute__((ext_vector_type(4)));
typedef float  f32x4  __attribute__((ext_vector_type(4)));
typedef uint16_t u16x8 __attribute__((ext_vector_type(8)));

// ---------------------------------------------------------------------------
// K1 (verbatim R17, best-measured): fused tproj + sgemm + x-copy.
// Block = (ks in [0,16), fo in [0,32)). T slab read once -> butterfly ->
// Tproj LDS (8 Walsh projections, masks {0,1,2,4,8,16,3,24}); x staged
// inline as MFMA A-frags (dbuf); bf16 Pp[ks][o'=f*8+p][n] partials.
// ---------------------------------------------------------------------------
__global__ __launch_bounds__(256, 2) void fused_kernel(const float* __restrict__ x,
                                                       const float* __restrict__ Tm,
                                                       float* __restrict__ out,
                                                       __bf16* __restrict__ Pp) {
    __shared__ __bf16 Bs[32][136];       // Tproj slab [o'_local][k_local], pad 8
    __shared__ __bf16 As[2][4][256][8];  // x A-frag dbuf (32 KB)

    const int tid  = threadIdx.x;
    const int lane = tid & 63;
    const int wid  = tid >> 6;
    const int fr   = lane & 15, fg = lane >> 4;
    const int bid  = blockIdx.x;
    const int ks   = bid & 15;
    const int fo   = bid >> 4;           // f-group of 4
    const int k0   = ks * 128;

    // ---- x -> out copy (block covers 4 KB: row bid>>1, half bid&1)
    {
        const int row = bid >> 1;
        const int off = (bid & 1) * 1024 + tid * 4;
        float4 v = *reinterpret_cast<const float4*>(&x[row * IN_F + off]);
        *reinterpret_cast<float4*>(&out[row * OC + off]) = v;
    }

    // ---- issue x chunk-0 loads early (latency hides under butterflies)
    float4 xs[8];
    const int kslot = tid & 7;
    const int nrow8 = tid >> 3;          // n = p*32 + nrow8
    #pragma unroll
    for (int p = 0; p < 8; ++p)
        xs[p] = *reinterpret_cast<const float4*>(&x[(p * 32 + nrow8) * IN_F + k0 + kslot * 4]);

    // ---- tproj: 2 (k,f) pairs per thread (sequential; keeps VGPR < 128)
    #pragma unroll 1
    for (int r = 0; r < 2; ++r) {
        const int idx = r * 256 + tid;
        const int fl  = idx & 3;
        const int kl  = idx >> 2;        // 0..127
        const float* src = Tm + (size_t)(k0 + kl) * OD + (fo * 4 + fl) * KD;

        float v[32];
        #pragma unroll
        for (int q = 0; q < 8; ++q) {
            f32x4 w = *reinterpret_cast<const f32x4*>(src + q * 4);
            v[q * 4]     = w[0];
            v[q * 4 + 1] = w[1];
            v[q * 4 + 2] = w[2];
            v[q * 4 + 3] = w[3];
        }

        float s1[16], d1[16];
        #pragma unroll
        for (int e = 0; e < 16; ++e) { s1[e] = v[2*e] + v[2*e+1]; d1[e] = v[2*e] - v[2*e+1]; }
        float s2[8], d2[8];
        #pragma unroll
        for (int e = 0; e < 8; ++e)  { s2[e] = s1[2*e] + s1[2*e+1]; d2[e] = s1[2*e] - s1[2*e+1]; }
        float s3[4], d3[4];
        #pragma unroll
        for (int e = 0; e < 4; ++e)  { s3[e] = s2[2*e] + s2[2*e+1]; d3[e] = s2[2*e] - s2[2*e+1]; }
        float s4[2], d4[2];
        #pragma unroll
        for (int e = 0; e < 2; ++e)  { s4[e] = s3[2*e] + s3[2*e+1]; d4[e] = s3[2*e] - s3[2*e+1]; }
        const float s5 = s4[0] + s4[1];
        const float d5 = s4[0] - s4[1];

        float pr[8];
        pr[0] = s5;
        { float s = 0.f;
          #pragma unroll
          for (int e = 0; e < 16; ++e) s += d1[e];
          pr[1] = s; }
        { float s = 0.f;
          #pragma unroll
          for (int e = 0; e < 8; ++e) s += d2[e];
          pr[2] = s; }
        pr[3] = (d3[0] + d3[1]) + (d3[2] + d3[3]);
        pr[4] = d4[0] + d4[1];
        pr[5] = d5;
        { float s = 0.f;
          #pragma unroll
          for (int g = 0; g < 8; ++g) s += d1[2*g] - d1[2*g+1];
          pr[6] = s; }
        pr[7] = s3[0] - s3[1] - s3[2] + s3[3];

        #pragma unroll
        for (int p = 0; p < 8; ++p)
            Bs[fl * 8 + p][kl] = (__bf16)pr[p];
    }

    // ---- write x chunk 0 into As[0]
    #pragma unroll
    for (int p = 0; p < 8; ++p) {
        bf16x4 b = { (__bf16)xs[p].x, (__bf16)xs[p].y, (__bf16)xs[p].z, (__bf16)xs[p].w };
        *reinterpret_cast<bf16x4*>(&As[0][kslot >> 1][p * 32 + nrow8][(kslot & 1) * 4]) = b;
    }
    __syncthreads();

    // ---- MFMA loop: 4 chunks of 32 k; acc[mi][oi], wave owns 64 n x 32 o'
    f32x4 acc[4][2] = {};

    #pragma unroll 1
    for (int c = 0; c < 4; ++c) {
        const int buf = c & 1;
        if (c < 3) {
            #pragma unroll
            for (int p = 0; p < 8; ++p)
                xs[p] = *reinterpret_cast<const float4*>(
                    &x[(p * 32 + nrow8) * IN_F + k0 + (c + 1) * 32 + kslot * 4]);
        }

        bf16x8 bfrag[2];
        #pragma unroll
        for (int oi = 0; oi < 2; ++oi)
            bfrag[oi] = *reinterpret_cast<const bf16x8*>(&Bs[oi * 16 + fr][c * 32 + fg * 8]);
        #pragma unroll
        for (int mi = 0; mi < 4; ++mi) {
            bf16x8 af = *reinterpret_cast<const bf16x8*>(&As[buf][fg][wid * 64 + mi * 16 + fr][0]);
            acc[mi][0] = __builtin_amdgcn_mfma_f32_16x16x32_bf16(af, bfrag[0], acc[mi][0], 0, 0, 0);
            acc[mi][1] = __builtin_amdgcn_mfma_f32_16x16x32_bf16(af, bfrag[1], acc[mi][1], 0, 0, 0);
        }

        if (c < 3) {
            __syncthreads();             // all waves done with As[buf^1] readers
            #pragma unroll
            for (int p = 0; p < 8; ++p) {
                bf16x4 b = { (__bf16)xs[p].x, (__bf16)xs[p].y, (__bf16)xs[p].z, (__bf16)xs[p].w };
                *reinterpret_cast<bf16x4*>(&As[buf ^ 1][kslot >> 1][p * 32 + nrow8][(kslot & 1) * 4]) = b;
            }
            __syncthreads();
        }
    }

    // ---- epilogue: Pp[ks][o' = fo*32 + oi*16 + fr][n = wid*64+mi*16+fg*4+r] bf16
    __bf16* dst = Pp + (size_t)ks * OPN;
    #pragma unroll
    for (int mi = 0; mi < 4; ++mi) {
        #pragma unroll
        for (int oi = 0; oi < 2; ++oi) {
            const int op = fo * 32 + oi * 16 + fr;
            const int nb = wid * 64 + mi * 16 + fg * 4;
            bf16x4 v = { (__bf16)acc[mi][oi][0], (__bf16)acc[mi][oi][1],
                         (__bf16)acc[mi][oi][2], (__bf16)acc[mi][oi][3] };
            *reinterpret_cast<bf16x4*>(&dst[(size_t)op * NR + nb]) = v;
        }
    }
}

// ---------------------------------------------------------------------------
// K2 (R23): TWO-TIER screen. Tier-1 hot loop: projections 0-3 only (ONE
// broadcast ds_read_b128 + 4 |d| + max tree). Tier-1 survivors (~200 on
// this data) check projections 4-7 from LDS (cheap). Exact fallback only
// if ALL 8 pass -- identical accept condition to R17's single-tier, which
// measured ZERO fallback events. Output bit-identical to R17.
// ---------------------------------------------------------------------------
__global__ __launch_bounds__(256, 2) void screen_kernel(const __bf16* __restrict__ Pp,
                                                        const float* __restrict__ x,
                                                        const float* __restrict__ Tm,
                                                        float* __restrict__ out) {
    __shared__ float P8s[256][8];
    __shared__ float part[4][64];

    const int f    = blockIdx.x;
    const int jq   = blockIdx.y;
    const int tid  = threadIdx.x;
    const int lane = tid & 63;
    const int wid  = tid >> 6;
    const int j    = jq * 64 + lane;

    // stage merged projections (16 bf16 partials, vectorized u16x8)
    {
        const int p  = tid >> 5;
        const int n0 = (tid & 31) * 8;
        const uint16_t* base = reinterpret_cast<const uint16_t*>(Pp)
                             + (size_t)(f * 8 + p) * NR + n0;
        float a[8] = {};
        #pragma unroll
        for (int ks = 0; ks < KSN; ++ks) {
            u16x8 v = *reinterpret_cast<const u16x8*>(base + (size_t)ks * OPN);
            #pragma unroll
            for (int e = 0; e < 8; ++e)
                a[e] += __builtin_bit_cast(float, (uint32_t)v[e] << 16);
        }
        #pragma unroll
        for (int e = 0; e < 8; ++e)
            P8s[n0 + e][p] = a[e];
    }
    __syncthreads();

    const f32x4 qj0 = *reinterpret_cast<const f32x4*>(&P8s[j][0]);
    const f32x4 qj1 = *reinterpret_cast<const f32x4*>(&P8s[j][4]);

    float acc = 0.f;
    const int i0 = wid * 64;
    #pragma unroll 2
    for (int ii = 0; ii < 64; ++ii) {
        const int i = i0 + ii;
        // tier 1: projections 0-3 (one broadcast b128)
        f32x4 r0 = *reinterpret_cast<const f32x4*>(&P8s[i][0]);
        f32x4 d0 = r0 - qj0;
        const float mx1 = fmaxf(fmaxf(fabsf(d0[0]), fabsf(d0[1])),
                                fmaxf(fabsf(d0[2]), fabsf(d0[3])));
        const bool ok1 = (mx1 < THRESH) && (i != j);

        if (__builtin_expect(__any(ok1), 0)) {
            // tier 2: projections 4-7 (rare; ~200 events total)
            bool ok2 = false;
            if (ok1) {
                f32x4 r1 = *reinterpret_cast<const f32x4*>(&P8s[i][4]);
                f32x4 d1 = r1 - qj1;
                const float mx2 = fmaxf(fmaxf(fabsf(d1[0]), fabsf(d1[1])),
                                        fmaxf(fabsf(d1[2]), fabsf(d1[3])));
                ok2 = mx2 < THRESH;
            }
            if (__builtin_expect(__any(ok2), 0)) {
                if (ok2) {
                    // exact fallback (all 8 projections passed; ~never on this data)
                    f32x4 ad[8] = {};
                    const float* xi = x + (size_t)i * IN_F;
                    const float* xj = x + (size_t)j * IN_F;
                    for (int k = 0; k < IN_F; ++k) {
                        const float dk = xi[k] - xj[k];
                        const float* tr = Tm + (size_t)k * OD + f * KD;
                        #pragma unroll
                        for (int q = 0; q < 8; ++q) {
                            f32x4 tv = *reinterpret_cast<const f32x4*>(tr + q * 4);
                            ad[q] += dk * tv;
                        }
                    }
                    float norm = 0.f;
                    #pragma unroll
                    for (int q = 0; q < 8; ++q)
                        norm += fabsf(ad[q][0]) + fabsf(ad[q][1])
                              + fabsf(ad[q][2]) + fabsf(ad[q][3]);
                    acc += __expf(-norm);
                }
            }
        }
    }

    if (wid == jq) acc += 1.0f;          // diagonal exp(0)=1, exact

    part[wid][lane] = acc;
    __syncthreads();
    if (tid < 64) {
        float s = part[0][tid] + part[1][tid] + part[2][tid] + part[3][tid];
        out[(jq * 64 + tid) * OC + IN_F + f] = s;
    }
}

extern "C" void kernel_launch(void* const* d_in, const int* in_sizes, int n_in,
                              void* d_out, int out_size, void* d_ws, size_t ws_size,
                              hipStream_t stream) {
    const float* x  = (const float*)d_in[0];   // [256, 2048] f32
    const float* Tm = (const float*)d_in[1];   // [2048, 4096] f32
    float* out = (float*)d_out;                // [256, 2176] f32

    __bf16* Pp = (__bf16*)d_ws;                // 8 MB: 16 bf16 o'-major partials

    fused_kernel<<<dim3(512), 256, 0, stream>>>(x, Tm, out, Pp);
    screen_kernel<<<dim3(128, 4), 256, 0, stream>>>(Pp, x, Tm, out);
}